// Round 12
// baseline (219.436 us; speedup 1.0000x reference)
//
#include <hip/hip_runtime.h>

// DoReFa dense: out = q_in(3-bit) @ (sign(W)*E) + b,  E = mean|W|
//   out[i,j] = (E/7) * sum_k r[i,k]*sign(W[k,j]),  r in 0..7 -- exact in i8 MFMA.
// R12: A operands fragment-packed (AFRAG) and loaded global->reg coalesced
//      (L2-friendly: 2 A-panels/XCD = 2MB; L1 serves 4-way wave redundancy);
//      B-only LDS (16KB/tile, R7-verified 128B-line-pair + XOR swizzle) ->
//      LDS-read wall halves. R11 champion structure otherwise: 256^2 tile,
//      16 waves 64x64, 3 buffers, 1 barrier/tile, counted vmcnt, setprio.

static constexpr int BATCH  = 8192;
static constexpr int IN_CH  = 4096;
static constexpr int NUNITS = 4096;
static constexpr int TPB    = 256;

typedef int v4i __attribute__((ext_vector_type(4)));

// ---- workspace layout ----
static constexpr size_t AF_OFF   = 0;                        // AFRAG[512][64][64][16]
static constexpr size_t AF_BYTES = (size_t)BATCH * IN_CH;    // 32 MB
static constexpr size_t BT_OFF   = AF_OFF + AF_BYTES;
static constexpr size_t BT_BYTES = (size_t)NUNITS * IN_CH;   // 16 MB
static constexpr int    NPART    = 4096;
static constexpr size_t PART_OFF = BT_OFF + BT_BYTES;
static constexpr size_t SCALE_OFF= PART_OFF + NPART * sizeof(float);

// -------------------------- sign(W) transpose to [N][K]  +  fused |W| partial sum
__global__ __launch_bounds__(TPB) void k_signT(const float* __restrict__ W,
                                               char* __restrict__ bt,
                                               float* __restrict__ partials) {
    __shared__ char tile[64][68];
    __shared__ float red[TPB];
    const int bk = blockIdx.x & 63;
    const int bn = blockIdx.x >> 6;
    const int t  = threadIdx.x;
    const int c  = t & 63;
    const int r0 = t >> 6;
    float asum = 0.f;
#pragma unroll
    for (int i = 0; i < 16; ++i) {
        int r = i * 4 + r0;
        float w = W[(size_t)(bk * 64 + r) * NUNITS + bn * 64 + c];
        asum += fabsf(w);
        tile[c][r] = (w > 0.f) ? 1 : ((w < 0.f) ? -1 : 0);
    }
    __syncthreads();
    const int n  = t >> 2;
    const int kk = (t & 3) * 16;
    char o[16];
#pragma unroll
    for (int j = 0; j < 16; ++j) o[j] = tile[n][kk + j];
    *(uint4*)(bt + (size_t)(bn * 64 + n) * IN_CH + bk * 64 + kk) = *(const uint4*)o;

    red[t] = asum;
    __syncthreads();
    for (int off = TPB / 2; off > 0; off >>= 1) {
        if (t < off) red[t] += red[t + off];
        __syncthreads();
    }
    if (t == 0) partials[blockIdx.x] = red[0];
}

// ------------------------------------------------------------- quantize A -> AFRAG
// AFRAG[mt][kt][lane][16]: element (lane, j) = q(x[mt*16 + (lane&15)][kt*64 + (lane>>4)*16 + j])
// (identical per-lane layout to R8's correctness-verified B fragment packing)
__device__ __forceinline__ unsigned int q4(float4 v) {
    unsigned int b0 = (unsigned int)(int)rintf(fminf(1.0f, fabsf(v.x)) * 7.0f);
    unsigned int b1 = (unsigned int)(int)rintf(fminf(1.0f, fabsf(v.y)) * 7.0f);
    unsigned int b2 = (unsigned int)(int)rintf(fminf(1.0f, fabsf(v.z)) * 7.0f);
    unsigned int b3 = (unsigned int)(int)rintf(fminf(1.0f, fabsf(v.w)) * 7.0f);
    return b0 | (b1 << 8) | (b2 << 16) | (b3 << 24);
}

__global__ __launch_bounds__(TPB) void k_quant_a(const float* __restrict__ x,
                                                 char* __restrict__ af,
                                                 const float* __restrict__ partials,
                                                 float* __restrict__ scale) {
    if (blockIdx.x == 0) {   // fused scale finalize (partials ready: same stream order)
        __shared__ float red[TPB];
        float s = 0.f;
        for (int i = threadIdx.x; i < NPART; i += TPB) s += partials[i];
        red[threadIdx.x] = s;
        __syncthreads();
        for (int off = TPB / 2; off > 0; off >>= 1) {
            if ((int)threadIdx.x < off) red[threadIdx.x] += red[threadIdx.x + off];
            __syncthreads();
        }
        if (threadIdx.x == 0) {
            float E = red[0] / (float)((size_t)IN_CH * NUNITS);
            *scale = E / 7.0f;
        }
        __syncthreads();
    }
    // 64 rows x 64 cols per block; LDS transpose to fragment order.
    __shared__ uint4 lds[64][5];   // [row][k-slot], +1 pad
    const int t  = threadIdx.x;
    const int br = blockIdx.x >> 6;      // 0..127 (row tile of 64)
    const int bc = blockIdx.x & 63;      // 0..63  (col tile of 64)
    const int r  = t >> 2;               // 0..63
    const int cs = t & 3;                // 0..3 (16-float chunk)
    const float4* xp = (const float4*)x + ((size_t)(br * 64 + r) * 1024 + bc * 16 + cs * 4);
    uint4 q;
    q.x = q4(xp[0]); q.y = q4(xp[1]); q.z = q4(xp[2]); q.w = q4(xp[3]);
    lds[r][cs] = q;
    __syncthreads();
    const int m    = t >> 6;             // 0..3
    const int lane = t & 63;
    uint4 o = lds[m * 16 + (lane & 15)][lane >> 4];
    *(uint4*)(af + ((((size_t)(br * 4 + m)) * 64 + bc) << 10) + lane * 16) = o;
}

// ---------------------------------------------------------------- GEMM
// 256x256 block tile, BK=64, 16 waves (4x4, wave tile 64x64), mfma_i32_16x16x64_i8.
// A: global fragment loads (4 x 1KB coalesced per wave per tile).
// B: LDS, 3 buffers x 16KB; line L (0..127) = B-row L (slots 0-3) || B-row L+128
// (slots 4-7); phys slot = logical ^ (L&7)  [R7-verified conflict-free].
__device__ __forceinline__ void gload_lds16(const void* g, void* l) {
    __builtin_amdgcn_global_load_lds((const __attribute__((address_space(1))) void*)g,
                                     (__attribute__((address_space(3))) void*)l,
                                     16, 0, 0);
}

#define VMCNT1   asm volatile("s_waitcnt vmcnt(1)" ::: "memory")
#define VMCNT0   asm volatile("s_waitcnt vmcnt(0)" ::: "memory")
#define LGKM0    asm volatile("s_waitcnt lgkmcnt(0)" ::: "memory")
#define SCHEDB   __builtin_amdgcn_sched_barrier(0)
#define BARRIER  __builtin_amdgcn_s_barrier()
#define PRIO1    __builtin_amdgcn_s_setprio(1)
#define PRIO0    __builtin_amdgcn_s_setprio(0)

static constexpr int NT = IN_CH / 64;   // 64 K-tiles

__global__ __launch_bounds__(1024, 4) void k_gemm(const char* __restrict__ AF,
                                                  const char* __restrict__ BT,
                                                  const float* __restrict__ scale_p,
                                                  const float* __restrict__ bias,
                                                  float* __restrict__ out) {
    __shared__ char Bs[3][16384];   // 48 KiB

    const int t    = threadIdx.x;                 // 0..1023
    const int bid  = blockIdx.x;                  // 512 blocks
    const int swzb = (bid & 7) * 64 + (bid >> 3); // XCD swizzle (bijective: 512%8==0)
    const int bRow = swzb >> 4;                   // 0..31
    const int bCol = swzb & 15;                   // 0..15
    const int lane = t & 63;
    const int wid  = t >> 6;                      // 0..15
    const int wr   = wid >> 2;                    // 0..3
    const int wc   = wid & 3;                     // 0..3
    const int lr   = lane & 15;
    const int lk4  = lane >> 4;                   // 0..3

    // A fragment base: mt = bRow*16 + wr*4 + m
    const char* aBaseF = AF + (((size_t)(bRow * 16 + wr * 4) * 64) << 10) + lane * 16;

    // B read byte offsets (per n): row R = wc*64 + n*16 + lr; line = R&127;
    // logical slot = (R>>7)*4 + lk4; phys = logical ^ (line&7)
    int boff[4];
#pragma unroll
    for (int n = 0; n < 4; ++n) {
        const int R    = wc * 64 + n * 16 + lr;
        const int line = R & 127;
        const int phys = (((R >> 7) << 2) | lk4) ^ (line & 7);
        boff[n] = line * 128 + phys * 16;
    }

    // B staging: thread t -> dest line t>>3, phys slot t&7 (linear dest t*16)
    const int x_    = (t & 7) ^ ((t >> 3) & 7);
    const int srow  = (t >> 3) + ((x_ >> 2) << 7);
    const char* sB  = BT + (size_t)(bCol * 256 + srow) * IN_CH + ((x_ & 3) << 4);

    v4i acc[4][4] = {};

#define STAGE1(kt, STG)  gload_lds16(sB + (size_t)(kt) * 64, (STG) + t * 16)

#define TILE(kt, CUR, STG, GATE)                                                 \
    do {                                                                         \
        SCHEDB; LGKM0;                                                           \
        GATE;                                                                    \
        BARRIER; SCHEDB;                                                         \
        if ((kt) + 2 < NT) { STAGE1((kt) + 2, STG); }                            \
        v4i a_[4], b_[4];                                                        \
        _Pragma("unroll") for (int m = 0; m < 4; ++m)                            \
            a_[m] = *(const v4i*)(aBaseF + (((size_t)m * 64 + (kt)) << 10));     \
        _Pragma("unroll") for (int n = 0; n < 4; ++n)                            \
            b_[n] = *(const v4i*)((CUR) + boff[n]);                              \
        PRIO1;                                                                   \
        _Pragma("unroll") for (int m = 0; m < 4; ++m)                            \
            _Pragma("unroll") for (int n = 0; n < 4; ++n)                        \
                acc[m][n] = __builtin_amdgcn_mfma_i32_16x16x64_i8(               \
                    a_[m], b_[n], acc[m][n], 0, 0, 0);                           \
        PRIO0;                                                                   \
    } while (0)

    char* B0 = (char*)Bs[0];
    char* B1 = (char*)Bs[1];
    char* B2 = (char*)Bs[2];

    // prologue: stage B tiles 0,1 (2 issues outstanding)
    STAGE1(0, B0);
    STAGE1(1, B1);

    // tiles 0..62 (21 x 3 rotation), tail tile 63
    for (int T = 0; T < NT - 1; T += 3) {
        TILE(T,     B0, B2, VMCNT1);
        TILE(T + 1, B1, B0, VMCNT1);
        TILE(T + 2, B2, B1, VMCNT1);
    }
    TILE(NT - 1, B0, B2, VMCNT0);

    // ---- epilogue
    const float scale = *scale_p;
    const int orow0 = bRow * 256 + wr * 64;
    const int ocol0 = bCol * 256 + wc * 64;
#pragma unroll
    for (int m = 0; m < 4; ++m) {
#pragma unroll
        for (int n = 0; n < 4; ++n) {
            const int col = ocol0 + n * 16 + lr;
            const float bb = bias[col];
            const int rbase = orow0 + m * 16 + lk4 * 4;
#pragma unroll
            for (int j = 0; j < 4; ++j)
                out[(size_t)(rbase + j) * NUNITS + col] = scale * (float)acc[m][n][j] + bb;
        }
    }
#undef STAGE1
#undef TILE
}

// ---------------------------------------------------------------- launch
extern "C" void kernel_launch(void* const* d_in, const int* in_sizes, int n_in,
                              void* d_out, int out_size, void* d_ws, size_t ws_size,
                              hipStream_t stream) {
    const float* x  = (const float*)d_in[0];
    const float* W  = (const float*)d_in[1];
    const float* b  = (const float*)d_in[2];
    float* out      = (float*)d_out;

    char*  ws       = (char*)d_ws;
    char*  AF       = ws + AF_OFF;
    char*  BT       = ws + BT_OFF;
    float* partials = (float*)(ws + PART_OFF);
    float* scale    = (float*)(ws + SCALE_OFF);

    k_signT<<<(IN_CH / 64) * (NUNITS / 64), TPB, 0, stream>>>(W, BT, partials);
    k_quant_a<<<(BATCH / 64) * (IN_CH / 64), TPB, 0, stream>>>(x, AF, partials, scale);
    k_gemm<<<(BATCH / 256) * (NUNITS / 256), 1024, 0, stream>>>(AF, BT, scale, b, out);
}